// Round 15
// baseline (278.406 us; speedup 1.0000x reference)
//
#include <hip/hip_runtime.h>
#include <hip/hip_bf16.h>

#define Mm 8
#define Nn 512
#define NEe 409
#define NIi 103
#define Bb 512
#define Dd 243
#define Tt 16
#define SPROW 640      // spike row bytes (i8): e[0:409) pad[409:512) i[512:615) pad[615:640)
#define WCROW 1152     // packed weight row bytes (i8): inter(512) | E-rec(512) | I-rec(128)
#define DEC_I 0.33333334f  // (float)(1.0 - 1.0/1.5)
#define NBLK 256
#define NPACK 4608     // pack-role blocks: Mm*Nn*WCROW/4/256
#define FLAGSTRIDE 16  // one flag per 64B cache line
#define SPINMAX 1000000L

typedef int v4i __attribute__((ext_vector_type(4)));
union LV { long l[2]; v4i v; };

__device__ __forceinline__ float quantf(float w) {
    // fake_quant forward == clip(round-half-even(w), -8, 7)  (step = 1.0)
    float q = rintf(w);
    return fminf(fmaxf(q, -8.0f), 7.0f);
}

// ---------------- fused prep: weight pack (blocks 0..4607) + ext_proj (4608..4863) --
// Pack role byte-identical to r11-verified x4 pack. Ext role: register-blocked 8x4
// per thread (tile 128b x 64n, 256 blocks = 1/CU), chunk d=32 — the per-element
// accumulation chain (ascending-d fmaf) is identical to the 9x-verified k_ext, so
// ext values are bit-identical; only the tiling/scheduling changed (2.7x better
// fma:ds_read ratio -> VALU-bound instead of LDS-bound).
__global__ void __launch_bounds__(256)
k_prep(const float* __restrict__ Wint, const float* __restrict__ WEE,
       const float* __restrict__ WEI, const float* __restrict__ WIE,
       const float* __restrict__ WII, signed char* __restrict__ Wc,
       const float* __restrict__ x, const float* __restrict__ Win,
       const float* __restrict__ bin, float* __restrict__ ext) {
    __shared__ float xs[32][132];    // [d-chunk][b 128 + pad]
    __shared__ float wsm[32][68];    // [d-chunk][n 64 + pad]
    const int wgid = blockIdx.x;

    if (wgid < NPACK) {
        // ---- pack role: 4 k's per thread (r11-verified) ----
        int q = wgid * 256 + threadIdx.x;            // quad index; grid covers exactly
        int k0 = (q * 4) % WCROW;
        int n  = ((q * 4) / WCROW) & (Nn - 1);
        int m  = (q * 4) / (WCROW * Nn);
        char out4[4];
#pragma unroll
        for (int j = 0; j < 4; ++j) {
            int k = k0 + j;
            float w = 0.0f;
            if (k < 512) {
                if (k < NEe) w = Wint[((((m + 7) & 7) * Nn) + n) * NEe + k];
            } else if (k < 1024) {
                int jj = k - 512;
                if (jj < NEe) w = (n < NEe) ? WEE[((m * NEe) + n) * NEe + jj]
                                            : WEI[((m * NIi) + (n - NEe)) * NEe + jj];
            } else {
                int jj = k - 1024;
                if (jj < NIi) w = (n < NEe) ? WIE[((m * NEe) + n) * NIi + jj]
                                            : WII[((m * NIi) + (n - NEe)) * NIi + jj];
            }
            out4[j] = (signed char)(int)quantf(w);
        }
        *(int*)&Wc[q * 4] = *(int*)out4;
        return;
    }

    // ---- ext role: 256 blocks = m(8) x bt(4) x nt(8); tile 128b x 64n, 8x4/thread --
    const int bid = wgid - NPACK;
    const int m  = bid >> 5;
    const int bt = (bid >> 3) & 3;
    const int nt = bid & 7;
    const int b0 = bt * 128, n0 = nt * 64;
    const int t = threadIdx.x;
    const int tb8 = (t & 15) * 8;        // 16 groups x 8 = 128 b
    const int tn4 = (t >> 4) * 4;        // 16 groups x 4 = 64 n
    const int xr = t >> 1;               // x staging row 0..127
    const int xc = (t & 1) * 16;         // x staging d-offset
    const int wr = t >> 2;               // w staging row 0..63
    const int wc = (t & 3) * 8;          // w staging d-offset
    float c[8][4];
#pragma unroll
    for (int i = 0; i < 8; ++i)
#pragma unroll
        for (int j = 0; j < 4; ++j) c[i][j] = 0.0f;

    for (int d0 = 0; d0 < Dd; d0 += 32) {
#pragma unroll
        for (int j = 0; j < 16; ++j) {
            int d = d0 + xc + j;
            xs[xc + j][xr] = (d < Dd) ? x[(b0 + xr) * Dd + d] : 0.0f;
        }
#pragma unroll
        for (int j = 0; j < 8; ++j) {
            int d = d0 + wc + j;
            wsm[wc + j][wr] = (d < Dd) ? quantf(Win[((m * Nn) + n0 + wr) * Dd + d]) : 0.0f;
        }
        __syncthreads();
        const int dmax = min(32, Dd - d0);
        for (int d = 0; d < dmax; ++d) {
            float4 av0 = *(const float4*)&xs[d][tb8];
            float4 av1 = *(const float4*)&xs[d][tb8 + 4];
            float4 wv  = *(const float4*)&wsm[d][tn4];
            float a[8] = {av0.x, av0.y, av0.z, av0.w, av1.x, av1.y, av1.z, av1.w};
            float wq[4] = {wv.x, wv.y, wv.z, wv.w};
#pragma unroll
            for (int i = 0; i < 8; ++i)
#pragma unroll
                for (int j = 0; j < 4; ++j)
                    c[i][j] = fmaf(a[i], wq[j], c[i][j]);
        }
        __syncthreads();
    }
#pragma unroll
    for (int i = 0; i < 8; ++i)
#pragma unroll
        for (int j = 0; j < 4; ++j) {
            float val = __fadd_rn(c[i][j], bin[m * Nn + n0 + tn4 + j]);
            ext[(size_t)(m * Bb + b0 + tb8 + i) * Nn + n0 + tn4 + j] = val;
        }
}

// ---------------- persistent 16-tick LIF: neighborhood dataflow sync (r13 verbatim) -
// 256 blocks x 512 thr, tile 64b x 128n. Each block waits only on the 12 flags of
// mesh-groups {m-1, m, m+1} x nt(4) at its bt (RAW on m-1/m, WAR on m+1's ping-pong
// read). Flags monotone + poison-tolerant; publish = spike agent-atomics ->
// __syncthreads vmcnt drain -> relaxed flag store (r8-verified mechanism).
__global__ void __launch_bounds__(512, 2)
k_ticks(const signed char* __restrict__ Wc,
        signed char* __restrict__ Sp0,
        signed char* __restrict__ Sp1,
        const float* __restrict__ ext,
        float* __restrict__ out,
        int* __restrict__ flags) {
    __shared__ __align__(16) signed char sA[2][64][128];    // 16 KB
    __shared__ __align__(16) signed char sB[2][128][128];   // 32 KB

    const int wg = blockIdx.x;           // 256: m(8) x bt(8) x nt(4)
    const int m  = wg & 7;               // mesh -> XCD affinity heuristic
    const int bt = (wg >> 3) & 7;
    const int nt = wg >> 6;              // 0..3
    const int b0 = bt * 64;
    const int n0 = nt * 128;
    const int pm = (m + 7) & 7;
    const int nm = (m + 1) & 7;

    const int tid  = threadIdx.x;        // 0..511
    const int w    = tid >> 6;           // 0..7
    const int lane = tid & 63;
    const int bh   = w & 1;              // 32-row half of b-tile
    const int nh   = w >> 1;             // 0..3: 32-col slice of n-tile
    const int quad = lane >> 4;
    const int li   = lane & 15;
    const int lx   = li & 7;             // read-side swizzle key

    // wait-set flag index for tid<12: mesh {pm,m,nm}[tid>>2], nt'=tid&3, same bt
    int waitIdx = 0;
    if (tid < 12) {
        int g  = tid >> 2;
        int mm = (g == 0) ? pm : ((g == 1) ? m : nm);
        waitIdx = (((tid & 3) << 6) | (bt << 3) | mm) * FLAGSTRIDE;
    }

    // staging coords: A 1 chunk/thread (64 rows x 8), B 2 chunks/thread (128 rows x 8)
    const int rowA  = tid >> 3;
    const int cnkA  = tid & 7;
    const int gcolA = cnkA * 16;
    const int scolA = (cnkA ^ (rowA & 7)) * 16;
    int rowB[2], gcolB[2], scolB[2];
#pragma unroll
    for (int j = 0; j < 2; ++j) {
        int ch = tid + j * 512;
        rowB[j]  = ch >> 3;
        int cnk  = ch & 7;
        gcolB[j] = cnk * 16;
        scolB[j] = (cnk ^ (rowB[j] & 7)) * 16;
    }

    float decs[2]; int offs[2]; int nels[2];
#pragma unroll
    for (int tn = 0; tn < 2; ++tn) {
        int n = n0 + nh * 32 + tn * 16 + li;
        nels[tn] = n;
        decs[tn] = (n < NEe) ? 0.5f : DEC_I;
        offs[tn] = (n < NEe) ? n : (n + 103);   // i-region of spike row starts at 512
    }
    const int bbase = b0 + bh * 32;

    const signed char* WcBase = Wc + (size_t)(m * Nn + n0) * WCROW;

    // per-thread persistent state in registers for all 16 ticks
    float extr[2][2][4];
#pragma unroll
    for (int tb = 0; tb < 2; ++tb)
#pragma unroll
        for (int tn = 0; tn < 2; ++tn)
#pragma unroll
            for (int r = 0; r < 4; ++r) {
                int b = bbase + tb * 16 + quad * 4 + r;
                extr[tb][tn][r] = ext[(size_t)(m * Bb + b) * Nn + nels[tn]];
            }
    float vmem[2][2][4];
    int cnt[2][2];
#pragma unroll
    for (int tb = 0; tb < 2; ++tb)
#pragma unroll
        for (int tn = 0; tn < 2; ++tn) {
            cnt[tb][tn] = 0;
#pragma unroll
            for (int r = 0; r < 4; ++r) vmem[tb][tn][r] = 0.0f;
        }

    // tick-0 pad-zeroing (r9/r11-verified): nt==0 blocks zero the pad bytes of their
    // 64 rows in both buffers; visible to consumers via this block's flag(1) post
    if (nt == 0) {
        for (int idx = tid; idx < 64 * 128 * 2; idx += 512) {
            int bufsel = idx >> 13;
            int rr = (idx >> 7) & 63;
            int p  = idx & 127;
            int off = (p < 103) ? (409 + p) : (615 + (p - 103));
            signed char* base = (bufsel ? Sp1 : Sp0) + (size_t)(m * Bb + b0 + rr) * SPROW + off;
            __hip_atomic_store(base, (signed char)0, __ATOMIC_RELAXED, __HIP_MEMORY_SCOPE_AGENT);
        }
    }

    for (int t = 0; t < Tt; ++t) {
        signed char* SR = (t & 1) ? Sp1 : Sp0;
        signed char* SW = (t & 1) ? Sp0 : Sp1;
        signed char* AbasePrev = SR + (size_t)(pm * Bb + b0) * SPROW;
        signed char* AbaseOwn  = SR + (size_t)(m  * Bb + b0) * SPROW;

        // neighborhood wait: 12 flags {pm,m,nm} x nt' at level t (t>=1).
        if (t > 0) {
            if (tid < 12) {
                long spin = 0;
                while (__hip_atomic_load(&flags[waitIdx],
                                         __ATOMIC_RELAXED, __HIP_MEMORY_SCOPE_AGENT) < t) {
                    __builtin_amdgcn_s_sleep(2);
                    if (++spin > SPINMAX) break;   // bail: wrong answer beats a hang
                }
            }
            __syncthreads();
        }

        float c[2][2][4];

        if (t == 0) {
            // spikes all zero: c = ((ext + 0) + 0) + 0, exact fadd chain as GEMM path
#pragma unroll
            for (int tb = 0; tb < 2; ++tb)
#pragma unroll
                for (int tn = 0; tn < 2; ++tn)
#pragma unroll
                    for (int r = 0; r < 4; ++r)
                        c[tb][tn][r] = __fadd_rn(__fadd_rn(__fadd_rn(extr[tb][tn][r], 0.0f), 0.0f), 0.0f);
        } else {
            v4i acc[2][2];
#pragma unroll
            for (int tb = 0; tb < 2; ++tb)
#pragma unroll
                for (int tn = 0; tn < 2; ++tn) acc[tb][tn] = (v4i){0, 0, 0, 0};

            // stage chunk 0 (k0=0 -> prev-mesh e segment); A via agent atomics (L3)
            {
                long* ap = (long*)(AbasePrev + (size_t)rowA * SPROW + gcolA);
                LV tmp;
                tmp.l[0] = __hip_atomic_load(ap,     __ATOMIC_RELAXED, __HIP_MEMORY_SCOPE_AGENT);
                tmp.l[1] = __hip_atomic_load(ap + 1, __ATOMIC_RELAXED, __HIP_MEMORY_SCOPE_AGENT);
                *(v4i*)&sA[0][rowA][scolA] = tmp.v;
#pragma unroll
                for (int j = 0; j < 2; ++j)
                    *(v4i*)&sB[0][rowB[j]][scolB[j]] =
                        *(const v4i*)(WcBase + (size_t)rowB[j] * WCROW + gcolB[j]);
            }
            __syncthreads();

            for (int it = 0; it < 9; ++it) {
                const int buf = it & 1;
                v4i nA, nB[2];
                if (it < 8) {
                    const int k0 = (it + 1) * 128;
                    signed char* ab; int ko;
                    if (k0 < 512) { ab = AbasePrev; ko = k0; }
                    else          { ab = AbaseOwn;  ko = k0 - 512; }
                    long* ap = (long*)(ab + (size_t)rowA * SPROW + ko + gcolA);
                    LV tmp;
                    tmp.l[0] = __hip_atomic_load(ap,     __ATOMIC_RELAXED, __HIP_MEMORY_SCOPE_AGENT);
                    tmp.l[1] = __hip_atomic_load(ap + 1, __ATOMIC_RELAXED, __HIP_MEMORY_SCOPE_AGENT);
                    nA = tmp.v;
#pragma unroll
                    for (int j = 0; j < 2; ++j)
                        nB[j] = *(const v4i*)(WcBase + (size_t)rowB[j] * WCROW + k0 + gcolB[j]);
                }
                // compute current chunk: 2 k-steps of 64 (swizzled fragment reads)
#pragma unroll
                for (int ks = 0; ks < 128; ks += 64) {
                    const int c0 = (((ks >> 4) + quad) ^ lx) * 16;
                    v4i af0 = *(const v4i*)&sA[buf][bh * 32 + li][c0];
                    v4i af1 = *(const v4i*)&sA[buf][bh * 32 + 16 + li][c0];
#pragma unroll
                    for (int tn = 0; tn < 2; ++tn) {
                        v4i bfr = *(const v4i*)&sB[buf][nh * 32 + tn * 16 + li][c0];
                        acc[0][tn] = __builtin_amdgcn_mfma_i32_16x16x64_i8(af0, bfr, acc[0][tn], 0, 0, 0);
                        acc[1][tn] = __builtin_amdgcn_mfma_i32_16x16x64_i8(af1, bfr, acc[1][tn], 0, 0, 0);
                    }
                }
                if (it < 8) {
                    const int nb = buf ^ 1;
                    *(v4i*)&sA[nb][rowA][scolA] = nA;
#pragma unroll
                    for (int j = 0; j < 2; ++j)
                        *(v4i*)&sB[nb][rowB[j]][scolB[j]] = nB[j];
                }
                __syncthreads();
                // segment flushes preserve the reference's exact fp32 add order:
                // c = ((ext_proj+inter) + Erec) + Irec; each partial an exact integer.
                if (it == 3) {
#pragma unroll
                    for (int tb = 0; tb < 2; ++tb)
#pragma unroll
                        for (int tn = 0; tn < 2; ++tn) {
#pragma unroll
                            for (int r = 0; r < 4; ++r)
                                c[tb][tn][r] = __fadd_rn(extr[tb][tn][r], (float)acc[tb][tn][r]);
                            acc[tb][tn] = (v4i){0, 0, 0, 0};
                        }
                } else if (it == 7 || it == 8) {
#pragma unroll
                    for (int tb = 0; tb < 2; ++tb)
#pragma unroll
                        for (int tn = 0; tn < 2; ++tn) {
#pragma unroll
                            for (int r = 0; r < 4; ++r)
                                c[tb][tn][r] = __fadd_rn(c[tb][tn][r], (float)acc[tb][tn][r]);
                            acc[tb][tn] = (v4i){0, 0, 0, 0};
                        }
                }
            }
        }

        // LIF update, exact np op order: v' = (v*decay) + c; spike iff v' >= 1.0
        // spikes published via agent-scope atomic byte stores (write-through)
#pragma unroll
        for (int tb = 0; tb < 2; ++tb)
#pragma unroll
            for (int tn = 0; tn < 2; ++tn)
#pragma unroll
                for (int r = 0; r < 4; ++r) {
                    float vn = __fadd_rn(__fmul_rn(vmem[tb][tn][r], decs[tn]), c[tb][tn][r]);
                    int s = (vn >= 1.0f) ? 1 : 0;
                    vmem[tb][tn][r] = s ? 0.0f : vn;
                    cnt[tb][tn] += s << (r * 8);
                    if (t < Tt - 1) {
                        int b = bbase + tb * 16 + quad * 4 + r;
                        signed char* sp = SW + (size_t)(m * Bb + b) * SPROW + offs[tn];
                        __hip_atomic_store(sp, (signed char)s,
                                           __ATOMIC_RELAXED, __HIP_MEMORY_SCOPE_AGENT);
                    }
                }
        // post completion flag for tick t (covers this tick's reads AND writes)
        if (t < Tt - 1) {
            __syncthreads();              // vmcnt(0): spike atomics + LDS use complete
            if (tid == 0)
                __hip_atomic_store(&flags[wg * FLAGSTRIDE], t + 1,
                                   __ATOMIC_RELAXED, __HIP_MEMORY_SCOPE_AGENT);
        }
    }

    // out[b][m*N + n] = spike count (single write at the end)
#pragma unroll
    for (int tb = 0; tb < 2; ++tb)
#pragma unroll
        for (int tn = 0; tn < 2; ++tn)
#pragma unroll
            for (int r = 0; r < 4; ++r) {
                int b = bbase + tb * 16 + quad * 4 + r;
                out[(size_t)b * (Mm * Nn) + m * Nn + nels[tn]] =
                    (float)((cnt[tb][tn] >> (r * 8)) & 0xff);
            }
}

extern "C" void kernel_launch(void* const* d_in, const int* in_sizes, int n_in,
                              void* d_out, int out_size, void* d_ws, size_t ws_size,
                              hipStream_t stream) {
    const float* x    = (const float*)d_in[0];
    const float* Win  = (const float*)d_in[1];
    const float* bin  = (const float*)d_in[2];
    const float* Wint = (const float*)d_in[3];
    const float* WEE  = (const float*)d_in[4];
    const float* WEI  = (const float*)d_in[5];
    const float* WIE  = (const float*)d_in[6];
    const float* WII  = (const float*)d_in[7];
    float* out = (float*)d_out;

    char* ws = (char*)d_ws;
    signed char* Wc  = (signed char*)ws;                       // 8*512*1152 = 4,718,592
    signed char* Sp0 = (signed char*)(ws + 4718592);           // 8*512*640  = 2,621,440
    signed char* Sp1 = Sp0 + 2621440;
    int* flags = (int*)(ws + 4718592 + 2 * 2621440);           // 256*64 B (poison-tolerant)
    float* extw = (float*)(ws + 4718592 + 2 * 2621440 + 32768);  // 8,388,608

    k_prep<<<NPACK + 256, 256, 0, stream>>>(Wint, WEE, WEI, WIE, WII, Wc,
                                            x, Win, bin, extw);
    k_ticks<<<NBLK, 512, 0, stream>>>(Wc, Sp0, Sp1, (const float*)extw, out, flags);
}

// Round 16
// 226.256 us; speedup vs baseline: 1.2305x; 1.2305x over previous
//
#include <hip/hip_runtime.h>
#include <hip/hip_bf16.h>

#define Mm 8
#define Nn 512
#define NEe 409
#define NIi 103
#define Bb 512
#define Dd 243
#define Tt 16
#define SPROW 640      // spike row bytes (i8): e[0:409) pad[409:512) i[512:615) pad[615:640)
#define WCROW 1152     // packed weight row bytes (i8): inter(512) | E-rec(512) | I-rec(128)
#define DEC_I 0.33333334f  // (float)(1.0 - 1.0/1.5)
#define NBLK 256
#define FLAGSTRIDE 16  // one flag per 64B cache line
#define SPINMAX 1000000L

typedef int v4i __attribute__((ext_vector_type(4)));
union LV { long l[2]; v4i v; };

__device__ __forceinline__ float quantf(float w) {
    // fake_quant forward == clip(round-half-even(w), -8, 7)  (step = 1.0)
    float q = rintf(w);
    return fminf(fmaxf(q, -8.0f), 7.0f);
}

// ---------------- pack quantized recurrent weights as i8, 4 k's per thread ----------
// (r11/r13-verified; separate kernel so pack keeps its own register budget — r15 lesson)
__global__ void k_pack(const float* __restrict__ Wint, const float* __restrict__ WEE,
                       const float* __restrict__ WEI, const float* __restrict__ WIE,
                       const float* __restrict__ WII, signed char* __restrict__ Wc) {
    int q = blockIdx.x * 256 + threadIdx.x;          // quad index
    if (q >= (Mm * Nn * WCROW) / 4) return;
    int k0 = (q * 4) % WCROW;
    int n  = ((q * 4) / WCROW) & (Nn - 1);
    int m  = (q * 4) / (WCROW * Nn);
    char out4[4];
#pragma unroll
    for (int j = 0; j < 4; ++j) {
        int k = k0 + j;
        float w = 0.0f;
        if (k < 512) {
            if (k < NEe) w = Wint[((((m + 7) & 7) * Nn) + n) * NEe + k];
        } else if (k < 1024) {
            int jj = k - 512;
            if (jj < NEe) w = (n < NEe) ? WEE[((m * NEe) + n) * NEe + jj]
                                        : WEI[((m * NIi) + (n - NEe)) * NEe + jj];
        } else {
            int jj = k - 1024;
            if (jj < NIi) w = (n < NEe) ? WIE[((m * NEe) + n) * NIi + jj]
                                        : WII[((m * NIi) + (n - NEe)) * NIi + jj];
        }
        out4[j] = (signed char)(int)quantf(w);
    }
    *(int*)&Wc[q * 4] = *(int*)out4;
}

// ---------------- ext_proj = x @ qW_in^T + b_in  (r8-verified chunk-64, verbatim) ----
__global__ void k_ext(const float* __restrict__ x, const float* __restrict__ Win,
                      const float* __restrict__ bin, float* __restrict__ ext) {
    __shared__ float xs[64][68];
    __shared__ float wsm[64][68];
    const int bid = blockIdx.x;          // 512 blocks: m(8) x bt(8) x nt(8)
    const int m  = bid >> 6;
    const int bt = (bid >> 3) & 7;
    const int nt = bid & 7;
    const int b0 = bt * 64, n0 = nt * 64;
    const int t = threadIdx.x;
    const int tb4 = (t & 15) * 4;
    const int tn4 = (t >> 4) * 4;
    const int sr = t >> 2;
    const int sc = (t & 3) * 16;
    float c[4][4];
#pragma unroll
    for (int i = 0; i < 4; ++i)
#pragma unroll
        for (int j = 0; j < 4; ++j) c[i][j] = 0.0f;

    for (int d0 = 0; d0 < Dd; d0 += 64) {
#pragma unroll
        for (int j = 0; j < 16; ++j) {
            int d = d0 + sc + j;
            float xv = 0.0f, wv = 0.0f;
            if (d < Dd) {
                xv = x[(b0 + sr) * Dd + d];
                wv = quantf(Win[((m * Nn) + n0 + sr) * Dd + d]);
            }
            xs[sc + j][sr] = xv;
            wsm[sc + j][sr] = wv;
        }
        __syncthreads();
        const int dmax = min(64, Dd - d0);
        for (int d = 0; d < dmax; ++d) {
            float4 av = *(const float4*)&xs[d][tb4];
            float4 wv = *(const float4*)&wsm[d][tn4];
            float a[4] = {av.x, av.y, av.z, av.w};
            float wq[4] = {wv.x, wv.y, wv.z, wv.w};
#pragma unroll
            for (int i = 0; i < 4; ++i)
#pragma unroll
                for (int j = 0; j < 4; ++j)
                    c[i][j] = fmaf(a[i], wq[j], c[i][j]);
        }
        __syncthreads();
    }
#pragma unroll
    for (int i = 0; i < 4; ++i)
#pragma unroll
        for (int j = 0; j < 4; ++j) {
            float val = __fadd_rn(c[i][j], bin[m * Nn + n0 + tn4 + j]);
            ext[(size_t)(m * Bb + b0 + tb4 + i) * Nn + n0 + tn4 + j] = val;
        }
}

// ---------------- persistent 16-tick LIF: r13 structure, BK=256 K-chunks ------------
// 256 blocks x 512 thr, tile 64b x 128n, neighborhood dataflow sync (r13-verified).
// BK 128->256 halves loop barriers (9->5 chunks: [0,256)[256,512)[512,768)[768,1024)
// [1024,1152-half)); segment flushes after chunk1 (inter), chunk3 (E), epilogue (I)
// keep the reference's exact fp32 add order. LDS 96 KB, 1 block/CU, swizzle key
// widened to 4 bits (cnk ^ row&15 / (ks>>4)+quad ^ li) — same 2-way-free banks.
__global__ void __launch_bounds__(512, 2)
k_ticks(const signed char* __restrict__ Wc,
        signed char* __restrict__ Sp0,
        signed char* __restrict__ Sp1,
        const float* __restrict__ ext,
        float* __restrict__ out,
        int* __restrict__ flags) {
    __shared__ __align__(16) signed char sA[2][64][256];    // 32 KB
    __shared__ __align__(16) signed char sB[2][128][256];   // 64 KB

    const int wg = blockIdx.x;           // 256: m(8) x bt(8) x nt(4)
    const int m  = wg & 7;               // mesh -> XCD affinity heuristic
    const int bt = (wg >> 3) & 7;
    const int nt = wg >> 6;              // 0..3
    const int b0 = bt * 64;
    const int n0 = nt * 128;
    const int pm = (m + 7) & 7;
    const int nm = (m + 1) & 7;

    const int tid  = threadIdx.x;        // 0..511
    const int w    = tid >> 6;           // 0..7
    const int lane = tid & 63;
    const int bh   = w & 1;              // 32-row half of b-tile
    const int nh   = w >> 1;             // 0..3: 32-col slice of n-tile
    const int quad = lane >> 4;
    const int li   = lane & 15;          // 4-bit swizzle key

    // wait-set flag index for tid<12: mesh {pm,m,nm}[tid>>2], nt'=tid&3, same bt
    int waitIdx = 0;
    if (tid < 12) {
        int g  = tid >> 2;
        int mm = (g == 0) ? pm : ((g == 1) ? m : nm);
        waitIdx = (((tid & 3) << 6) | (bt << 3) | mm) * FLAGSTRIDE;
    }

    // staging coords (BK=256): A 2 chunks/thread (64 rows x 16), B 4 (128 rows x 16)
    int rowA[2], cnkA[2], gcolA[2], scolA[2];
#pragma unroll
    for (int j = 0; j < 2; ++j) {
        int ch = tid + j * 512;
        rowA[j]  = ch >> 4;
        cnkA[j]  = ch & 15;
        gcolA[j] = cnkA[j] * 16;
        scolA[j] = (cnkA[j] ^ (rowA[j] & 15)) * 16;
    }
    int rowB[4], cnkB[4], gcolB[4], scolB[4];
#pragma unroll
    for (int j = 0; j < 4; ++j) {
        int ch = tid + j * 512;
        rowB[j]  = ch >> 4;
        cnkB[j]  = ch & 15;
        gcolB[j] = cnkB[j] * 16;
        scolB[j] = (cnkB[j] ^ (rowB[j] & 15)) * 16;
    }

    float decs[2]; int offs[2]; int nels[2];
#pragma unroll
    for (int tn = 0; tn < 2; ++tn) {
        int n = n0 + nh * 32 + tn * 16 + li;
        nels[tn] = n;
        decs[tn] = (n < NEe) ? 0.5f : DEC_I;
        offs[tn] = (n < NEe) ? n : (n + 103);   // i-region of spike row starts at 512
    }
    const int bbase = b0 + bh * 32;

    const signed char* WcBase = Wc + (size_t)(m * Nn + n0) * WCROW;

    // per-thread persistent state in registers for all 16 ticks
    float extr[2][2][4];
#pragma unroll
    for (int tb = 0; tb < 2; ++tb)
#pragma unroll
        for (int tn = 0; tn < 2; ++tn)
#pragma unroll
            for (int r = 0; r < 4; ++r) {
                int b = bbase + tb * 16 + quad * 4 + r;
                extr[tb][tn][r] = ext[(size_t)(m * Bb + b) * Nn + nels[tn]];
            }
    float vmem[2][2][4];
    int cnt[2][2];
#pragma unroll
    for (int tb = 0; tb < 2; ++tb)
#pragma unroll
        for (int tn = 0; tn < 2; ++tn) {
            cnt[tb][tn] = 0;
#pragma unroll
            for (int r = 0; r < 4; ++r) vmem[tb][tn][r] = 0.0f;
        }

    // tick-0 pad-zeroing (r9/r11-verified): nt==0 blocks zero the pad bytes of their
    // 64 rows in both buffers; visible to consumers via this block's flag(1) post
    if (nt == 0) {
        for (int idx = tid; idx < 64 * 128 * 2; idx += 512) {
            int bufsel = idx >> 13;
            int rr = (idx >> 7) & 63;
            int p  = idx & 127;
            int off = (p < 103) ? (409 + p) : (615 + (p - 103));
            signed char* base = (bufsel ? Sp1 : Sp0) + (size_t)(m * Bb + b0 + rr) * SPROW + off;
            __hip_atomic_store(base, (signed char)0, __ATOMIC_RELAXED, __HIP_MEMORY_SCOPE_AGENT);
        }
    }

    for (int t = 0; t < Tt; ++t) {
        signed char* SR = (t & 1) ? Sp1 : Sp0;
        signed char* SW = (t & 1) ? Sp0 : Sp1;
        signed char* AbasePrev = SR + (size_t)(pm * Bb + b0) * SPROW;
        signed char* AbaseOwn  = SR + (size_t)(m  * Bb + b0) * SPROW;

        // neighborhood wait: 12 flags {pm,m,nm} x nt' at level t (t>=1).
        if (t > 0) {
            if (tid < 12) {
                long spin = 0;
                while (__hip_atomic_load(&flags[waitIdx],
                                         __ATOMIC_RELAXED, __HIP_MEMORY_SCOPE_AGENT) < t) {
                    __builtin_amdgcn_s_sleep(2);
                    if (++spin > SPINMAX) break;   // bail: wrong answer beats a hang
                }
            }
            __syncthreads();
        }

        float c[2][2][4];

        if (t == 0) {
            // spikes all zero: c = ((ext + 0) + 0) + 0, exact fadd chain as GEMM path
#pragma unroll
            for (int tb = 0; tb < 2; ++tb)
#pragma unroll
                for (int tn = 0; tn < 2; ++tn)
#pragma unroll
                    for (int r = 0; r < 4; ++r)
                        c[tb][tn][r] = __fadd_rn(__fadd_rn(__fadd_rn(extr[tb][tn][r], 0.0f), 0.0f), 0.0f);
        } else {
            v4i acc[2][2];
#pragma unroll
            for (int tb = 0; tb < 2; ++tb)
#pragma unroll
                for (int tn = 0; tn < 2; ++tn) acc[tb][tn] = (v4i){0, 0, 0, 0};

            // stage chunk 0 ([0,256) of prev-mesh e segment); A via agent atomics (L3)
#pragma unroll
            for (int j = 0; j < 2; ++j) {
                long* ap = (long*)(AbasePrev + (size_t)rowA[j] * SPROW + gcolA[j]);
                LV tmp;
                tmp.l[0] = __hip_atomic_load(ap,     __ATOMIC_RELAXED, __HIP_MEMORY_SCOPE_AGENT);
                tmp.l[1] = __hip_atomic_load(ap + 1, __ATOMIC_RELAXED, __HIP_MEMORY_SCOPE_AGENT);
                *(v4i*)&sA[0][rowA[j]][scolA[j]] = tmp.v;
            }
#pragma unroll
            for (int j = 0; j < 4; ++j)
                *(v4i*)&sB[0][rowB[j]][scolB[j]] =
                    *(const v4i*)(WcBase + (size_t)rowB[j] * WCROW + gcolB[j]);
            __syncthreads();

            // main chunks 0..3 (full 256-wide), prefetch next (chunk 4 is half-width)
            for (int it = 0; it < 4; ++it) {
                const int buf = it & 1;
                const int k0 = (it + 1) * 256;          // 256,512,768,1024
                signed char* ab; int ko;
                if (k0 < 512) { ab = AbasePrev; ko = k0; }
                else          { ab = AbaseOwn;  ko = k0 - 512; }
                const int kw = (it == 3) ? 128 : 256;   // chunk 4 has 128 valid bytes
                v4i nA[2], nB[4];
                bool ldA[2], ldB[4];
#pragma unroll
                for (int j = 0; j < 2; ++j) {
                    ldA[j] = (gcolA[j] < kw);
                    if (ldA[j]) {
                        long* ap = (long*)(ab + (size_t)rowA[j] * SPROW + ko + gcolA[j]);
                        LV tmp;
                        tmp.l[0] = __hip_atomic_load(ap,     __ATOMIC_RELAXED, __HIP_MEMORY_SCOPE_AGENT);
                        tmp.l[1] = __hip_atomic_load(ap + 1, __ATOMIC_RELAXED, __HIP_MEMORY_SCOPE_AGENT);
                        nA[j] = tmp.v;
                    }
                }
#pragma unroll
                for (int j = 0; j < 4; ++j) {
                    ldB[j] = (gcolB[j] < kw);
                    if (ldB[j])
                        nB[j] = *(const v4i*)(WcBase + (size_t)rowB[j] * WCROW + k0 + gcolB[j]);
                }
                // compute current chunk: 4 k-steps of 64 (swizzled fragment reads)
#pragma unroll
                for (int ks = 0; ks < 256; ks += 64) {
                    const int c0 = (((ks >> 4) + quad) ^ li) * 16;
                    v4i af0 = *(const v4i*)&sA[buf][bh * 32 + li][c0];
                    v4i af1 = *(const v4i*)&sA[buf][bh * 32 + 16 + li][c0];
#pragma unroll
                    for (int tn = 0; tn < 2; ++tn) {
                        v4i bfr = *(const v4i*)&sB[buf][nh * 32 + tn * 16 + li][c0];
                        acc[0][tn] = __builtin_amdgcn_mfma_i32_16x16x64_i8(af0, bfr, acc[0][tn], 0, 0, 0);
                        acc[1][tn] = __builtin_amdgcn_mfma_i32_16x16x64_i8(af1, bfr, acc[1][tn], 0, 0, 0);
                    }
                }
                const int nb = buf ^ 1;
#pragma unroll
                for (int j = 0; j < 2; ++j)
                    if (ldA[j]) *(v4i*)&sA[nb][rowA[j]][scolA[j]] = nA[j];
#pragma unroll
                for (int j = 0; j < 4; ++j)
                    if (ldB[j]) *(v4i*)&sB[nb][rowB[j]][scolB[j]] = nB[j];
                __syncthreads();
                // segment flushes: exact fp32 add order c = ((ext+inter)+E)+I
                if (it == 1) {
#pragma unroll
                    for (int tb = 0; tb < 2; ++tb)
#pragma unroll
                        for (int tn = 0; tn < 2; ++tn) {
#pragma unroll
                            for (int r = 0; r < 4; ++r)
                                c[tb][tn][r] = __fadd_rn(extr[tb][tn][r], (float)acc[tb][tn][r]);
                            acc[tb][tn] = (v4i){0, 0, 0, 0};
                        }
                } else if (it == 3) {
#pragma unroll
                    for (int tb = 0; tb < 2; ++tb)
#pragma unroll
                        for (int tn = 0; tn < 2; ++tn) {
#pragma unroll
                            for (int r = 0; r < 4; ++r)
                                c[tb][tn][r] = __fadd_rn(c[tb][tn][r], (float)acc[tb][tn][r]);
                            acc[tb][tn] = (v4i){0, 0, 0, 0};
                        }
                }
            }
            // epilogue: chunk 4 ([1024,1152), 128 valid bytes -> 2 k-steps), buf 0
#pragma unroll
            for (int ks = 0; ks < 128; ks += 64) {
                const int c0 = (((ks >> 4) + quad) ^ li) * 16;
                v4i af0 = *(const v4i*)&sA[0][bh * 32 + li][c0];
                v4i af1 = *(const v4i*)&sA[0][bh * 32 + 16 + li][c0];
#pragma unroll
                for (int tn = 0; tn < 2; ++tn) {
                    v4i bfr = *(const v4i*)&sB[0][nh * 32 + tn * 16 + li][c0];
                    acc[0][tn] = __builtin_amdgcn_mfma_i32_16x16x64_i8(af0, bfr, acc[0][tn], 0, 0, 0);
                    acc[1][tn] = __builtin_amdgcn_mfma_i32_16x16x64_i8(af1, bfr, acc[1][tn], 0, 0, 0);
                }
            }
#pragma unroll
            for (int tb = 0; tb < 2; ++tb)
#pragma unroll
                for (int tn = 0; tn < 2; ++tn)
#pragma unroll
                    for (int r = 0; r < 4; ++r)
                        c[tb][tn][r] = __fadd_rn(c[tb][tn][r], (float)acc[tb][tn][r]);
        }

        // LIF update, exact np op order: v' = (v*decay) + c; spike iff v' >= 1.0
        // spikes published via agent-scope atomic byte stores (write-through)
#pragma unroll
        for (int tb = 0; tb < 2; ++tb)
#pragma unroll
            for (int tn = 0; tn < 2; ++tn)
#pragma unroll
                for (int r = 0; r < 4; ++r) {
                    float vn = __fadd_rn(__fmul_rn(vmem[tb][tn][r], decs[tn]), c[tb][tn][r]);
                    int s = (vn >= 1.0f) ? 1 : 0;
                    vmem[tb][tn][r] = s ? 0.0f : vn;
                    cnt[tb][tn] += s << (r * 8);
                    if (t < Tt - 1) {
                        int b = bbase + tb * 16 + quad * 4 + r;
                        signed char* sp = SW + (size_t)(m * Bb + b) * SPROW + offs[tn];
                        __hip_atomic_store(sp, (signed char)s,
                                           __ATOMIC_RELAXED, __HIP_MEMORY_SCOPE_AGENT);
                    }
                }
        // post completion flag for tick t (covers this tick's reads AND writes)
        if (t < Tt - 1) {
            __syncthreads();              // vmcnt(0): spike atomics + LDS use complete
            if (tid == 0)
                __hip_atomic_store(&flags[wg * FLAGSTRIDE], t + 1,
                                   __ATOMIC_RELAXED, __HIP_MEMORY_SCOPE_AGENT);
        }
    }

    // out[b][m*N + n] = spike count (single write at the end)
#pragma unroll
    for (int tb = 0; tb < 2; ++tb)
#pragma unroll
        for (int tn = 0; tn < 2; ++tn)
#pragma unroll
            for (int r = 0; r < 4; ++r) {
                int b = bbase + tb * 16 + quad * 4 + r;
                out[(size_t)b * (Mm * Nn) + m * Nn + nels[tn]] =
                    (float)((cnt[tb][tn] >> (r * 8)) & 0xff);
            }
}

extern "C" void kernel_launch(void* const* d_in, const int* in_sizes, int n_in,
                              void* d_out, int out_size, void* d_ws, size_t ws_size,
                              hipStream_t stream) {
    const float* x    = (const float*)d_in[0];
    const float* Win  = (const float*)d_in[1];
    const float* bin  = (const float*)d_in[2];
    const float* Wint = (const float*)d_in[3];
    const float* WEE  = (const float*)d_in[4];
    const float* WEI  = (const float*)d_in[5];
    const float* WIE  = (const float*)d_in[6];
    const float* WII  = (const float*)d_in[7];
    float* out = (float*)d_out;

    char* ws = (char*)d_ws;
    signed char* Wc  = (signed char*)ws;                       // 8*512*1152 = 4,718,592
    signed char* Sp0 = (signed char*)(ws + 4718592);           // 8*512*640  = 2,621,440
    signed char* Sp1 = Sp0 + 2621440;
    int* flags = (int*)(ws + 4718592 + 2 * 2621440);           // 256*64 B (poison-tolerant)
    float* extw = (float*)(ws + 4718592 + 2 * 2621440 + 32768);  // 8,388,608

    k_pack<<<(Mm * Nn * WCROW / 4 + 255) / 256, 256, 0, stream>>>(Wint, WEE, WEI, WIE, WII, Wc);
    k_ext<<<512, 256, 0, stream>>>(x, Win, bin, extw);
    k_ticks<<<NBLK, 512, 0, stream>>>(Wc, Sp0, Sp1, (const float*)extw, out, flags);
}